// Round 7
// baseline (12653.220 us; speedup 1.0000x reference)
//
#include <hip/hip_runtime.h>

// Problem constants (B,S,F,L) = (512, 1024, 64, 128)
constexpr int Bn = 512;
constexpr int Sn = 1024;
constexpr int Fn = 64;
constexpr int Ln = 128;
constexpr int Gn = 4 * Ln;  // 512 gate rows (i,f,g,o)
constexpr int CH = 16;      // encoder pre-chunk: steps per in-kernel x-GEMM
constexpr int NCH = Sn / CH;

typedef unsigned int u32;
typedef _Float16 h2 __attribute__((ext_vector_type(2)));
typedef _Float16 h8 __attribute__((ext_vector_type(8)));
typedef float f4 __attribute__((ext_vector_type(4)));

// ---- cross-lane helpers (dense epilogue reduce) ----
template <int CTRL>
__device__ __forceinline__ float dpp_mov(float v) {
  return __int_as_float(__builtin_amdgcn_mov_dpp(__float_as_int(v), CTRL, 0xF, 0xF, true));
}
template <int CTRL>
__device__ __forceinline__ float dpp_add(float v) {
  return v + dpp_mov<CTRL>(v);
}
// 0xB1 = quad_perm xor1; 0x4E = quad_perm xor2
__device__ __forceinline__ float swz_xor4(float v) {  // lane ^ 4
  return __int_as_float(__builtin_amdgcn_ds_swizzle(__float_as_int(v), 0x101F));
}

__device__ __forceinline__ float fdot2(u32 a, u32 b, float c) {
  return __builtin_amdgcn_fdot2(__builtin_bit_cast(h2, a), __builtin_bit_cast(h2, b), c, false);
}
__device__ __forceinline__ float fsig(float v) {
  return __builtin_amdgcn_rcpf(1.0f + __expf(-v));
}
__device__ __forceinline__ h8 as_h8(uint4 v) { return __builtin_bit_cast(h8, v); }

// Pack encoder weights + dense weights to fp16 in workspace.
__global__ void pack_kernel(const float* __restrict__ Wih, const float* __restrict__ Whh,
                            const float* __restrict__ Wd,
                            _Float16* __restrict__ WhE, _Float16* __restrict__ WxE,
                            _Float16* __restrict__ WdH) {
  const int i = blockIdx.x * 256 + threadIdx.x;  // grid covers 65536
  if (i < Gn * Ln) WhE[i] = (_Float16)Whh[i];
  if (i < Gn * Fn) WxE[i] = (_Float16)Wih[i];
  if (i < Fn * Ln) WdH[i] = (_Float16)Wd[i];
}

// Fold decoder dense into the recurrence (fp32 math, fp16 result).
__global__ void combine_dec_kernel(const float* __restrict__ Wih, const float* __restrict__ Whh,
                                   const float* __restrict__ bih, const float* __restrict__ bhh,
                                   const float* __restrict__ Wd, const float* __restrict__ bd,
                                   _Float16* __restrict__ WcH, float* __restrict__ bc) {
  const int t = blockIdx.x;   // gate row 0..511
  const int l = threadIdx.x;  // latent col 0..127
  float s = Whh[t * Ln + l];
#pragma unroll
  for (int j = 0; j < Fn; ++j) s += Wih[t * Fn + j] * Wd[j * Ln + l];
  WcH[t * Ln + l] = (_Float16)s;
  if (l == 0) {
    float sb = bih[t] + bhh[t];
#pragma unroll
    for (int j = 0; j < Fn; ++j) sb += Wih[t * Fn + j] * bd[j];
    bc[t] = sb;
  }
}

// r12 MFMA persistent kernel = r11 structure with CH 32->16.
// r6 counters: MfmaUtil 53.6 / VALUBusy 55.5 / Occupancy 44% / LDS 70656 B.
// Issue model: ~1300 cyc/step issue vs 2250 measured -> ~45% stall; VGPR=64
// already meets the 8-wave/SIMD budget, ONLY the 64KB fp32 pre[] LDS caps
// occupancy at 2 blocks/CU. CH=16 halves pre to 32KB -> ~35.6KB/block ->
// 4 blocks/CU = 32 waves/CU (100%), FOUR independent barrier domains to fill
// the stall cycles. No precision change (pre stays fp32); chunk GEMM 2x more
// frequent (amortized ~1 MFMA/step, negligible; bx reload stays L2-hot).
// __launch_bounds__(512, 8) pins the 64-VGPR cap.
//
// Per step: gates[1x512] = h[1x128] @ W^T via mfma_f32_16x16x32_f16.
//  - A-frag (M=1 broadcast): every lane loads the same 16B h-slice -> all 16
//    A rows equal h; C rows are identical copies (no garbage/NaN).
//  - B-frag: lane l holds W[tile*16+(l&15)][(l>>4)*8+j] -> contiguous 16B row
//    slice; 16 uint4 loop-invariant in VGPRs.
//  - Wave w owns N-tiles {w, w+8, w+16, w+24} = i/f/g~/o blocks of latents
//    w*16..w*16+15 -> acc0..acc3[0] at lane l<16 are the 4 gate sums of
//    latent w*16+l: cell update is lane-local; only l<16 writes h.
// Encoder x-projection: chunked MFMA prepass every CH=16 steps into fp32 LDS
// pre[16x512] (M=16 tile, bias folded into acc init).
// Decoder: same loop minus pre (W_comb regs, bias from bc) + r9-verified
// dense epilogue (oj=t>>3, k8=t&7, xor1/2/4 reduce).
__global__ __launch_bounds__(512, 8)
void rae_mfma_kernel(const float* __restrict__ x,
                     const _Float16* __restrict__ WhE, const _Float16* __restrict__ WxE,
                     const float* __restrict__ bih_e, const float* __restrict__ bhh_e,
                     const _Float16* __restrict__ WcH, const float* __restrict__ bc,
                     const _Float16* __restrict__ WdH, const float* __restrict__ bd,
                     float* __restrict__ out) {
  const int t = threadIdx.x;
  const int w = t >> 6;    // wave 0..7
  const int l = t & 63;    // lane
  const int jj = l & 15;   // tile column
  const int g16 = l >> 4;  // K-slice group (A/B frag k = g16*8..g16*8+8)
  const int b = blockIdx.x;

  __shared__ float pre[CH * 512];        // 32 KB: x@Wx^T + b for current chunk
  __shared__ u32 xraw[CH * 36];          // 16 rows x 72 halfs (144B stride)
  __shared__ __align__(16) _Float16 hs[2][Ln];

  // ---- encoder B-frags: bh[g][kt], g=gate tile, kt=K-tile ----
  uint4 bh[4][4];
#pragma unroll
  for (int g = 0; g < 4; ++g) {
    const size_t row = (size_t)((w + 8 * g) * 16 + jj);
#pragma unroll
    for (int kt = 0; kt < 4; ++kt)
      bh[g][kt] = *(const uint4*)(WhE + row * 128 + kt * 32 + g16 * 8);
  }
  float be[4];  // encoder bias for this lane's gate column (used by chunk GEMM)
#pragma unroll
  for (int g = 0; g < 4; ++g) {
    const int row = (w + 8 * g) * 16 + jj;
    be[g] = bih_e[row] + bhh_e[row];
  }

  float c = 0.0f;  // cell state for latent w*16+jj (valid lanes l<16; other
                   // lane groups hold identical copies by construction)

  if (t < 64) ((u32*)&hs[0][0])[t] = 0u;  // zero h buffer 0
  const float* xb = x + (size_t)b * Sn * Fn;

  // ================= encoder: 64 chunks x 16 steps =================
  int s = 0;
  for (int ch = 0; ch < NCH; ++ch) {
    // ---- stage x chunk fp32->fp16 into xraw (coalesced float4) ----
    if (t < 16 * CH) {  // 16 threads per row x CH rows
      const int st = t >> 4, f0 = (t & 15) * 4;
      float4 v = *(const float4*)(xb + (size_t)(ch * CH + st) * Fn + f0);
      h2 p0 = {(_Float16)v.x, (_Float16)v.y};
      h2 p1 = {(_Float16)v.z, (_Float16)v.w};
      xraw[st * 36 + (t & 15) * 2] = __builtin_bit_cast(u32, p0);
      xraw[st * 36 + (t & 15) * 2 + 1] = __builtin_bit_cast(u32, p1);
    }
    __syncthreads();
    // ---- chunk GEMM: pre[st][gate] = x_st . Wx[gate] + be ----
    {
      uint4 bx[4][2];
#pragma unroll
      for (int g = 0; g < 4; ++g) {
        const size_t row = (size_t)((w + 8 * g) * 16 + jj);
#pragma unroll
        for (int kt = 0; kt < 2; ++kt)
          bx[g][kt] = *(const uint4*)(WxE + row * 64 + kt * 32 + g16 * 8);
      }
#pragma unroll
      for (int mt = 0; mt < CH / 16; ++mt) {  // 1 M-tile of 16 steps
        h8 a0 = as_h8(*(const uint4*)&xraw[(mt * 16 + jj) * 36 + g16 * 4]);
        h8 a1 = as_h8(*(const uint4*)&xraw[(mt * 16 + jj) * 36 + 16 + g16 * 4]);
#pragma unroll
        for (int g = 0; g < 4; ++g) {
          f4 acc = {be[g], be[g], be[g], be[g]};
          acc = __builtin_amdgcn_mfma_f32_16x16x32_f16(a0, as_h8(bx[g][0]), acc, 0, 0, 0);
          acc = __builtin_amdgcn_mfma_f32_16x16x32_f16(a1, as_h8(bx[g][1]), acc, 0, 0, 0);
          const int col = (w + 8 * g) * 16 + jj;
#pragma unroll
          for (int r = 0; r < 4; ++r)
            pre[(mt * 16 + g16 * 4 + r) * 512 + col] = acc[r];
        }
      }
    }
    __syncthreads();
    // ---- 16 recurrence steps ----
    for (int ss = 0; ss < CH; ++ss, ++s) {
      const int cur = s & 1, nx = cur ^ 1;
      const uint4* hp = (const uint4*)&hs[cur][0];
      f4 a0 = {0.f, 0.f, 0.f, 0.f}, a1 = a0, a2 = a0, a3 = a0;
#pragma unroll
      for (int kt = 0; kt < 4; ++kt) {
        h8 af = as_h8(hp[kt * 4 + g16]);  // broadcast: A rows all = h
        a0 = __builtin_amdgcn_mfma_f32_16x16x32_f16(af, as_h8(bh[0][kt]), a0, 0, 0, 0);
        a1 = __builtin_amdgcn_mfma_f32_16x16x32_f16(af, as_h8(bh[1][kt]), a1, 0, 0, 0);
        a2 = __builtin_amdgcn_mfma_f32_16x16x32_f16(af, as_h8(bh[2][kt]), a2, 0, 0, 0);
        a3 = __builtin_amdgcn_mfma_f32_16x16x32_f16(af, as_h8(bh[3][kt]), a3, 0, 0, 0);
      }
      const float p0 = pre[ss * 512 + (w + 0) * 16 + jj];
      const float p1 = pre[ss * 512 + (w + 8) * 16 + jj];
      const float p2 = pre[ss * 512 + (w + 16) * 16 + jj];
      const float p3 = pre[ss * 512 + (w + 24) * 16 + jj];
      __builtin_amdgcn_s_setprio(1);
      const float gi = fsig(a0[0] + p0);
      const float gf = fsig(a1[0] + p1);
      const float gg = __builtin_fmaf(2.0f, fsig(2.0f * (a2[0] + p2)), -1.0f);  // tanh
      const float go = fsig(a3[0] + p3);
      c = __builtin_fmaf(gf, c, gi * gg);
      const float tc = __builtin_fmaf(2.0f, fsig(2.0f * c), -1.0f);
      if (l < 16) hs[nx][w * 16 + jj] = (_Float16)(go * tc);
      __builtin_amdgcn_s_setprio(0);
      __syncthreads();
    }
  }

  // ================= decoder: 1024 steps =================
#pragma unroll
  for (int g = 0; g < 4; ++g) {  // reload B-frags with folded W_comb
    const size_t row = (size_t)((w + 8 * g) * 16 + jj);
#pragma unroll
    for (int kt = 0; kt < 4; ++kt)
      bh[g][kt] = *(const uint4*)(WcH + row * 128 + kt * 32 + g16 * 8);
  }
  float bdv[4];
#pragma unroll
  for (int g = 0; g < 4; ++g) bdv[g] = bc[(w + 8 * g) * 16 + jj];

  // dense epilogue mapping (r9-verified): oj = t>>3, k8 = t&7
  const int oj = t >> 3, k8 = t & 7;
  u32 dw[8];
  {
    const uint4* pd = (const uint4*)(WdH + oj * Ln + k8 * 16);
#pragma unroll
    for (int k = 0; k < 2; ++k) {
      uint4 v = pd[k];
      dw[4 * k] = v.x; dw[4 * k + 1] = v.y; dw[4 * k + 2] = v.z; dw[4 * k + 3] = v.w;
    }
  }
  const float dbias = bd[oj];
  float* op = out + (size_t)b * Sn * Fn + (size_t)(Sn - 1) * Fn + oj;

  for (int step = 0; step < Sn; ++step) {
    const int cur = step & 1, nx = cur ^ 1;
    const uint4* hp = (const uint4*)&hs[cur][0];
    f4 a0 = {bdv[0], bdv[0], bdv[0], bdv[0]};
    f4 a1 = {bdv[1], bdv[1], bdv[1], bdv[1]};
    f4 a2 = {bdv[2], bdv[2], bdv[2], bdv[2]};
    f4 a3 = {bdv[3], bdv[3], bdv[3], bdv[3]};
#pragma unroll
    for (int kt = 0; kt < 4; ++kt) {
      h8 af = as_h8(hp[kt * 4 + g16]);
      a0 = __builtin_amdgcn_mfma_f32_16x16x32_f16(af, as_h8(bh[0][kt]), a0, 0, 0, 0);
      a1 = __builtin_amdgcn_mfma_f32_16x16x32_f16(af, as_h8(bh[1][kt]), a1, 0, 0, 0);
      a2 = __builtin_amdgcn_mfma_f32_16x16x32_f16(af, as_h8(bh[2][kt]), a2, 0, 0, 0);
      a3 = __builtin_amdgcn_mfma_f32_16x16x32_f16(af, as_h8(bh[3][kt]), a3, 0, 0, 0);
    }
    __builtin_amdgcn_s_setprio(1);
    const float gi = fsig(a0[0]);
    const float gf = fsig(a1[0]);
    const float gg = __builtin_fmaf(2.0f, fsig(2.0f * a2[0]), -1.0f);
    const float go = fsig(a3[0]);
    c = __builtin_fmaf(gf, c, gi * gg);
    const float tc = __builtin_fmaf(2.0f, fsig(2.0f * c), -1.0f);
    if (l < 16) hs[nx][w * 16 + jj] = (_Float16)(go * tc);
    __builtin_amdgcn_s_setprio(0);
    __syncthreads();

    // dense on just-written h (buffer nx): out[b, S-1-step, oj].
    // Safe: next iter's h-write targets the other buffer; skew <1 barrier.
    const uint4* he = (const uint4*)&hs[nx][k8 * 16];
    float d = 0.0f;
    {
      uint4 v = he[0];
      d = fdot2(dw[0], v.x, d); d = fdot2(dw[1], v.y, d);
      d = fdot2(dw[2], v.z, d); d = fdot2(dw[3], v.w, d);
      v = he[1];
      d = fdot2(dw[4], v.x, d); d = fdot2(dw[5], v.y, d);
      d = fdot2(dw[6], v.z, d); d = fdot2(dw[7], v.w, d);
    }
    d = dpp_add<0xB1>(d);
    d = dpp_add<0x4E>(d);
    d += swz_xor4(d);
    if (k8 == 0) op[0] = d + dbias;
    op -= Fn;
  }
}

extern "C" void kernel_launch(void* const* d_in, const int* in_sizes, int n_in,
                              void* d_out, int out_size, void* d_ws, size_t ws_size,
                              hipStream_t stream) {
  const float* x     = (const float*)d_in[0];
  const float* Wih_e = (const float*)d_in[1];
  const float* Whh_e = (const float*)d_in[2];
  const float* bih_e = (const float*)d_in[3];
  const float* bhh_e = (const float*)d_in[4];
  const float* Wih_d = (const float*)d_in[5];
  const float* Whh_d = (const float*)d_in[6];
  const float* bih_d = (const float*)d_in[7];
  const float* bhh_d = (const float*)d_in[8];
  const float* Wd    = (const float*)d_in[9];
  const float* bd    = (const float*)d_in[10];
  float* out = (float*)d_out;

  // workspace: only the fixed fp16 weight copies + combined bias (~350 KB)
  _Float16* WhE = (_Float16*)d_ws;           // 512*128
  _Float16* WxE = WhE + Gn * Ln;             // 512*64
  _Float16* WcH = WxE + Gn * Fn;             // 512*128
  _Float16* WdH = WcH + Gn * Ln;             // 64*128
  float* bc = (float*)(WdH + Fn * Ln);       // 512

  pack_kernel<<<256, 256, 0, stream>>>(Wih_e, Whh_e, Wd, WhE, WxE, WdH);
  combine_dec_kernel<<<Gn, Ln, 0, stream>>>(Wih_d, Whh_d, bih_d, bhh_d, Wd, bd, WcH, bc);
  rae_mfma_kernel<<<Bn, 512, 0, stream>>>(x, WhE, WxE, bih_e, bhh_e,
                                          WcH, bc, WdH, bd, out);
}

// Round 8
// 1548.636 us; speedup vs baseline: 8.1706x; 8.1706x over previous
//
#include <hip/hip_runtime.h>

// Problem constants (B,S,F,L) = (512, 1024, 64, 128)
constexpr int Bn = 512;
constexpr int Sn = 1024;
constexpr int Fn = 64;
constexpr int Ln = 128;
constexpr int Gn = 4 * Ln;  // 512 gate rows (i,f,g,o)
constexpr int CH = 16;      // steps per in-kernel x-GEMM chunk
constexpr int NCH = Sn / CH;

typedef unsigned int u32;
typedef _Float16 h2 __attribute__((ext_vector_type(2)));
typedef _Float16 h8 __attribute__((ext_vector_type(8)));
typedef float f4 __attribute__((ext_vector_type(4)));

__device__ __forceinline__ float fsig(float v) {
  return __builtin_amdgcn_rcpf(1.0f + __expf(-v));
}
__device__ __forceinline__ h8 as_h8(uint4 v) { return __builtin_bit_cast(h8, v); }

// Pack encoder weights + dense weights to fp16 in workspace.
__global__ void pack_kernel(const float* __restrict__ Wih, const float* __restrict__ Whh,
                            const float* __restrict__ Wd,
                            _Float16* __restrict__ WhE, _Float16* __restrict__ WxE,
                            _Float16* __restrict__ WdH) {
  const int i = blockIdx.x * 256 + threadIdx.x;  // grid covers 65536
  if (i < Gn * Ln) WhE[i] = (_Float16)Whh[i];
  if (i < Gn * Fn) WxE[i] = (_Float16)Wih[i];
  if (i < Fn * Ln) WdH[i] = (_Float16)Wd[i];
}

// Fold decoder dense into the recurrence (fp32 math, fp16 result).
__global__ void combine_dec_kernel(const float* __restrict__ Wih, const float* __restrict__ Whh,
                                   const float* __restrict__ bih, const float* __restrict__ bhh,
                                   const float* __restrict__ Wd, const float* __restrict__ bd,
                                   _Float16* __restrict__ WcH, float* __restrict__ bc) {
  const int t = blockIdx.x;   // gate row 0..511
  const int l = threadIdx.x;  // latent col 0..127
  float s = Whh[t * Ln + l];
#pragma unroll
  for (int j = 0; j < Fn; ++j) s += Wih[t * Fn + j] * Wd[j * Ln + l];
  WcH[t * Ln + l] = (_Float16)s;
  if (l == 0) {
    float sb = bih[t] + bhh[t];
#pragma unroll
    for (int j = 0; j < Fn; ++j) sb += Wih[t * Fn + j] * bd[j];
    bc[t] = sb;
  }
}

// r13 M=2 MFMA persistent kernel: 256 blocks x 512 thr, 2 batch elems/block,
// exactly 1 block/CU (grid = CU count).
//
// r7 POST-MORTEM baked in: NO waves-per-EU cap (r7's (512,8) forced VGPR=32 ->
// bh spilled to global re-loads -> 35 GB fetch, 12.6 ms). Occupancy is GRID-
// bound (blocks/CU = grid/256), so the lever is useful work per block: MFMA
// count per block-step is M-independent -> M=2 elems fill 2 A-rows instead of
// r6's 1, halving per-element matrix work at the same instruction budget.
//
// Layouts (all m89-verified maps, numerically validated by r6):
//  - gates C[16x512] = A[16x128] @ W^T: A-frag lane reads h row (jj&1) ->
//    only 2 real h rows in LDS (hsb[buf][2][136 halfs]), broadcast-heavy.
//    C: col=l&15 within tile, row=(l>>4)*4+reg -> rows 0,1 = elems 0,1 sit in
//    lanes l<16 regs 0,1 -> lane-local cell update with c0,c1.
//  - wave w owns N-tiles {w,w+8,w+16,w+24} = i/f/g~/o of latents w*16..+16.
//  - pre[st][e][512] fp32 (64 KB LDS) from chunked x-GEMM: M=32 rows =
//    16 steps x 2 elems (2 M-tiles), bias folded into acc init. xraw rows
//    stride 36 u32 (bank-uniform).
//  - decoder dense as MFMA: C[2x64] = h @ Wd^T, 4 N-tiles on waves 0..3,
//    4kt each, rows 0,1 stored (coalesced 64B runs), bias added at store.
// One barrier per step; dense reads hs[nx] after the barrier (next step's
// h-write targets the other buffer; skew < 1 barrier -> safe, as r6).
__global__ __launch_bounds__(512)
void rae_mfma2_kernel(const float* __restrict__ x,
                      const _Float16* __restrict__ WhE, const _Float16* __restrict__ WxE,
                      const float* __restrict__ bih_e, const float* __restrict__ bhh_e,
                      const _Float16* __restrict__ WcH, const float* __restrict__ bc,
                      const _Float16* __restrict__ WdH, const float* __restrict__ bd,
                      float* __restrict__ out) {
  const int t = threadIdx.x;
  const int w = t >> 6;    // wave 0..7
  const int l = t & 63;    // lane
  const int jj = l & 15;   // tile column / A-row selector
  const int g16 = l >> 4;  // K-slice group (frag k = g16*8..g16*8+8)
  const int b = blockIdx.x;

  __shared__ float pre[CH * 2 * 512];  // [st][e][gate] 64 KB
  __shared__ u32 xraw[2 * CH * 36];    // [e][st][36 u32] (144B rows, bank-uniform)
  __shared__ u32 hsb[2 * 2 * 68];      // [buf][e][68 u32] = 128 halfs + pad

  // ---- encoder B-frags: bh[g][kt] = W row (w+8g)*16+jj, halfs kt*32+g16*8 ----
  uint4 bh[4][4];
  float be[4];
#pragma unroll
  for (int g = 0; g < 4; ++g) {
    const int row = (w + 8 * g) * 16 + jj;
#pragma unroll
    for (int kt = 0; kt < 4; ++kt)
      bh[g][kt] = *(const uint4*)(WhE + (size_t)row * 128 + kt * 32 + g16 * 8);
    be[g] = bih_e[row] + bhh_e[row];
  }

  float c0 = 0.0f, c1 = 0.0f;  // cell state, elems 0/1, latent w*16+l (lanes l<16)

  for (int i = t; i < 2 * 2 * 68; i += 512) hsb[i] = 0u;  // h = 0 both buffers
  __syncthreads();

  const float* xb = x + (size_t)b * 2 * Sn * Fn;

  // ================= encoder: 64 chunks x 16 steps =================
  int s = 0;
  for (int ch = 0; ch < NCH; ++ch) {
    // ---- stage x chunk fp32->fp16: 2 elems x 16 steps x 64 feats ----
    {
      const int e = t >> 8, st = (t >> 4) & 15, fq = t & 15;
      float4 v = *(const float4*)(xb + (size_t)e * Sn * Fn +
                                  (size_t)(ch * CH + st) * Fn + fq * 4);
      h2 p0 = {(_Float16)v.x, (_Float16)v.y};
      h2 p1 = {(_Float16)v.z, (_Float16)v.w};
      xraw[e * 576 + st * 36 + fq * 2] = __builtin_bit_cast(u32, p0);
      xraw[e * 576 + st * 36 + fq * 2 + 1] = __builtin_bit_cast(u32, p1);
    }
    __syncthreads();
    // ---- chunk GEMM: pre[st][e][col] = x[e,st,:] @ Wx^T[col] + be ----
    {
      uint4 bx0[4], bx1[4];
#pragma unroll
      for (int g = 0; g < 4; ++g) {
        const int row = (w + 8 * g) * 16 + jj;
        bx0[g] = *(const uint4*)(WxE + (size_t)row * 64 + g16 * 8);
        bx1[g] = *(const uint4*)(WxE + (size_t)row * 64 + 32 + g16 * 8);
      }
#pragma unroll
      for (int mt = 0; mt < 2; ++mt) {  // M-tile = elem
        h8 a0 = as_h8(*(const uint4*)&xraw[mt * 576 + jj * 36 + g16 * 4]);
        h8 a1 = as_h8(*(const uint4*)&xraw[mt * 576 + jj * 36 + 16 + g16 * 4]);
#pragma unroll
        for (int g = 0; g < 4; ++g) {
          f4 acc = {be[g], be[g], be[g], be[g]};
          acc = __builtin_amdgcn_mfma_f32_16x16x32_f16(a0, as_h8(bx0[g]), acc, 0, 0, 0);
          acc = __builtin_amdgcn_mfma_f32_16x16x32_f16(a1, as_h8(bx1[g]), acc, 0, 0, 0);
          const int col = (w + 8 * g) * 16 + jj;
#pragma unroll
          for (int r = 0; r < 4; ++r)  // C row = g16*4+r = step-in-chunk
            pre[(g16 * 4 + r) * 1024 + mt * 512 + col] = acc[r];
        }
      }
    }
    __syncthreads();
    // ---- 16 recurrence steps ----
    for (int ss = 0; ss < CH; ++ss, ++s) {
      const int cur = s & 1, nx = cur ^ 1;
      const u32* hb = &hsb[(cur * 2 + (jj & 1)) * 68];  // A row = elem jj&1
      f4 a0 = {0.f, 0.f, 0.f, 0.f}, a1 = a0, a2 = a0, a3 = a0;
#pragma unroll
      for (int kt = 0; kt < 4; ++kt) {
        h8 af = as_h8(*(const uint4*)&hb[kt * 16 + g16 * 4]);
        a0 = __builtin_amdgcn_mfma_f32_16x16x32_f16(af, as_h8(bh[0][kt]), a0, 0, 0, 0);
        a1 = __builtin_amdgcn_mfma_f32_16x16x32_f16(af, as_h8(bh[1][kt]), a1, 0, 0, 0);
        a2 = __builtin_amdgcn_mfma_f32_16x16x32_f16(af, as_h8(bh[2][kt]), a2, 0, 0, 0);
        a3 = __builtin_amdgcn_mfma_f32_16x16x32_f16(af, as_h8(bh[3][kt]), a3, 0, 0, 0);
      }
      if (l < 16) {  // rows 0,1 (elems 0,1) live in regs 0,1 of lanes l<16
        // elem 0
        float pi = pre[ss * 1024 + (w + 0) * 16 + l];
        float pf = pre[ss * 1024 + (w + 8) * 16 + l];
        float pg = pre[ss * 1024 + (w + 16) * 16 + l];
        float po = pre[ss * 1024 + (w + 24) * 16 + l];
        float gi = fsig(a0[0] + pi), gf = fsig(a1[0] + pf);
        float gg = __builtin_fmaf(2.f, fsig(2.f * (a2[0] + pg)), -1.f);
        float go = fsig(a3[0] + po);
        c0 = __builtin_fmaf(gf, c0, gi * gg);
        ((_Float16*)hsb)[(nx * 2 + 0) * 136 + w * 16 + l] =
            (_Float16)(go * __builtin_fmaf(2.f, fsig(2.f * c0), -1.f));
        // elem 1
        pi = pre[ss * 1024 + 512 + (w + 0) * 16 + l];
        pf = pre[ss * 1024 + 512 + (w + 8) * 16 + l];
        pg = pre[ss * 1024 + 512 + (w + 16) * 16 + l];
        po = pre[ss * 1024 + 512 + (w + 24) * 16 + l];
        gi = fsig(a0[1] + pi); gf = fsig(a1[1] + pf);
        gg = __builtin_fmaf(2.f, fsig(2.f * (a2[1] + pg)), -1.f);
        go = fsig(a3[1] + po);
        c1 = __builtin_fmaf(gf, c1, gi * gg);
        ((_Float16*)hsb)[(nx * 2 + 1) * 136 + w * 16 + l] =
            (_Float16)(go * __builtin_fmaf(2.f, fsig(2.f * c1), -1.f));
      }
      __syncthreads();
    }
  }

  // ================= decoder: 1024 steps =================
  float bdv[4];
#pragma unroll
  for (int g = 0; g < 4; ++g) {  // reload B-frags with folded W_comb
    const int row = (w + 8 * g) * 16 + jj;
#pragma unroll
    for (int kt = 0; kt < 4; ++kt)
      bh[g][kt] = *(const uint4*)(WcH + (size_t)row * 128 + kt * 32 + g16 * 8);
    bdv[g] = bc[row];
  }
  // dense B-frags (waves 0..3 own output tiles 0..3): out feature = w*16+jj
  uint4 dwf[4];
  float dbias = 0.0f;
  const int od = w * 16 + jj;
  if (w < 4) {
#pragma unroll
    for (int kt = 0; kt < 4; ++kt)
      dwf[kt] = *(const uint4*)(WdH + (size_t)od * 128 + kt * 32 + g16 * 8);
    dbias = bd[od];
  }
  float* outb = out + (size_t)b * 2 * Sn * Fn;

  for (int step = 0; step < Sn; ++step, ++s) {
    const int cur = s & 1, nx = cur ^ 1;
    const u32* hb = &hsb[(cur * 2 + (jj & 1)) * 68];
    f4 a0 = {bdv[0], bdv[0], bdv[0], bdv[0]};
    f4 a1 = {bdv[1], bdv[1], bdv[1], bdv[1]};
    f4 a2 = {bdv[2], bdv[2], bdv[2], bdv[2]};
    f4 a3 = {bdv[3], bdv[3], bdv[3], bdv[3]};
#pragma unroll
    for (int kt = 0; kt < 4; ++kt) {
      h8 af = as_h8(*(const uint4*)&hb[kt * 16 + g16 * 4]);
      a0 = __builtin_amdgcn_mfma_f32_16x16x32_f16(af, as_h8(bh[0][kt]), a0, 0, 0, 0);
      a1 = __builtin_amdgcn_mfma_f32_16x16x32_f16(af, as_h8(bh[1][kt]), a1, 0, 0, 0);
      a2 = __builtin_amdgcn_mfma_f32_16x16x32_f16(af, as_h8(bh[2][kt]), a2, 0, 0, 0);
      a3 = __builtin_amdgcn_mfma_f32_16x16x32_f16(af, as_h8(bh[3][kt]), a3, 0, 0, 0);
    }
    if (l < 16) {
      // elem 0 (bias already in acc init)
      float gi = fsig(a0[0]), gf = fsig(a1[0]);
      float gg = __builtin_fmaf(2.f, fsig(2.f * a2[0]), -1.f);
      float go = fsig(a3[0]);
      c0 = __builtin_fmaf(gf, c0, gi * gg);
      ((_Float16*)hsb)[(nx * 2 + 0) * 136 + w * 16 + l] =
          (_Float16)(go * __builtin_fmaf(2.f, fsig(2.f * c0), -1.f));
      // elem 1
      gi = fsig(a0[1]); gf = fsig(a1[1]);
      gg = __builtin_fmaf(2.f, fsig(2.f * a2[1]), -1.f);
      go = fsig(a3[1]);
      c1 = __builtin_fmaf(gf, c1, gi * gg);
      ((_Float16*)hsb)[(nx * 2 + 1) * 136 + w * 16 + l] =
          (_Float16)(go * __builtin_fmaf(2.f, fsig(2.f * c1), -1.f));
    }
    __syncthreads();

    // dense on just-written h (buffer nx): out[2b+e, S-1-step, od].
    if (w < 4) {
      const u32* hn = &hsb[(nx * 2 + (jj & 1)) * 68];
      f4 d = {0.f, 0.f, 0.f, 0.f};
#pragma unroll
      for (int kt = 0; kt < 4; ++kt) {
        h8 af = as_h8(*(const uint4*)&hn[kt * 16 + g16 * 4]);
        d = __builtin_amdgcn_mfma_f32_16x16x32_f16(af, as_h8(dwf[kt]), d, 0, 0, 0);
      }
      if (l < 16) {
        const size_t roff = (size_t)(Sn - 1 - step) * Fn + w * 16 + l;
        outb[roff] = d[0] + dbias;                       // elem 0
        outb[(size_t)Sn * Fn + roff] = d[1] + dbias;     // elem 1
      }
    }
  }
}

extern "C" void kernel_launch(void* const* d_in, const int* in_sizes, int n_in,
                              void* d_out, int out_size, void* d_ws, size_t ws_size,
                              hipStream_t stream) {
  const float* x     = (const float*)d_in[0];
  const float* Wih_e = (const float*)d_in[1];
  const float* Whh_e = (const float*)d_in[2];
  const float* bih_e = (const float*)d_in[3];
  const float* bhh_e = (const float*)d_in[4];
  const float* Wih_d = (const float*)d_in[5];
  const float* Whh_d = (const float*)d_in[6];
  const float* bih_d = (const float*)d_in[7];
  const float* bhh_d = (const float*)d_in[8];
  const float* Wd    = (const float*)d_in[9];
  const float* bd    = (const float*)d_in[10];
  float* out = (float*)d_out;

  // workspace: only the fixed fp16 weight copies + combined bias (~350 KB)
  _Float16* WhE = (_Float16*)d_ws;           // 512*128
  _Float16* WxE = WhE + Gn * Ln;             // 512*64
  _Float16* WcH = WxE + Gn * Fn;             // 512*128
  _Float16* WdH = WcH + Gn * Ln;             // 64*128
  float* bc = (float*)(WdH + Fn * Ln);       // 512

  pack_kernel<<<256, 256, 0, stream>>>(Wih_e, Whh_e, Wd, WhE, WxE, WdH);
  combine_dec_kernel<<<Gn, Ln, 0, stream>>>(Wih_d, Whh_d, bih_d, bhh_d, Wd, bd, WcH, bc);
  rae_mfma2_kernel<<<Bn / 2, 512, 0, stream>>>(x, WhE, WxE, bih_e, bhh_e,
                                               WcH, bc, WdH, bd, out);
}

// Round 9
// 1193.243 us; speedup vs baseline: 10.6041x; 1.2978x over previous
//
#include <hip/hip_runtime.h>

// Problem constants (B,S,F,L) = (512, 1024, 64, 128)
constexpr int Bn = 512;
constexpr int Sn = 1024;
constexpr int Fn = 64;
constexpr int Ln = 128;
constexpr int Gn = 4 * Ln;  // 512 gate rows (i,f,g,o)
constexpr int CH = 16;      // steps per in-kernel x-GEMM chunk
constexpr int NCH = Sn / CH;
constexpr int XST = 44;     // xraw row stride (u32): 8-way -> ~2-way GEMM reads
constexpr int PST = 1028;   // pre step-stride (floats): 1028%32=4 -> writes 2-way
constexpr int HST = 80;     // hsb elem stride (u32): h b128 reads conflict-free

typedef unsigned int u32;
typedef _Float16 h2 __attribute__((ext_vector_type(2)));
typedef _Float16 h8 __attribute__((ext_vector_type(8)));
typedef float f4 __attribute__((ext_vector_type(4)));

__device__ __forceinline__ float fsig(float v) {
  return __builtin_amdgcn_rcpf(1.0f + __expf(-v));
}
__device__ __forceinline__ h8 as_h8(uint4 v) { return __builtin_bit_cast(h8, v); }

// Pack encoder weights + dense weights to fp16 in workspace.
__global__ void pack_kernel(const float* __restrict__ Wih, const float* __restrict__ Whh,
                            const float* __restrict__ Wd,
                            _Float16* __restrict__ WhE, _Float16* __restrict__ WxE,
                            _Float16* __restrict__ WdH) {
  const int i = blockIdx.x * 256 + threadIdx.x;  // grid covers 65536
  if (i < Gn * Ln) WhE[i] = (_Float16)Whh[i];
  if (i < Gn * Fn) WxE[i] = (_Float16)Wih[i];
  if (i < Fn * Ln) WdH[i] = (_Float16)Wd[i];
}

// Fold decoder dense into the recurrence (fp32 math, fp16 result).
__global__ void combine_dec_kernel(const float* __restrict__ Wih, const float* __restrict__ Whh,
                                   const float* __restrict__ bih, const float* __restrict__ bhh,
                                   const float* __restrict__ Wd, const float* __restrict__ bd,
                                   _Float16* __restrict__ WcH, float* __restrict__ bc) {
  const int t = blockIdx.x;   // gate row 0..511
  const int l = threadIdx.x;  // latent col 0..127
  float s = Whh[t * Ln + l];
#pragma unroll
  for (int j = 0; j < Fn; ++j) s += Wih[t * Fn + j] * Wd[j * Ln + l];
  WcH[t * Ln + l] = (_Float16)s;
  if (l == 0) {
    float sb = bih[t] + bhh[t];
#pragma unroll
    for (int j = 0; j < Fn; ++j) sb += Wih[t * Fn + j] * bd[j];
    bc[t] = sb;
  }
}

// r15 = r13 (M=2 MFMA persistent, 256 blocks x 512 thr, 1 block/CU) + three
// counter-derived fixes. r8 PMC: SQ_LDS_BANK_CONFLICT 9.4e7 (179 cyc/step/CU):
//  (1) hsb elem stride 68->80 u32: h-read b128 bank base = 16*(jj&1)+4*g16
//      +16*kt -> the 8 distinct 16B reads are bank-disjoint (was: jj-parity
//      offset 4 collided with g16 groups). pre st-stride 1024->1028: C-write
//      banks get 16*(g16%2) spread -> 4-way becomes 2-way (free, m136).
//      xraw 36->44 u32: chunk-GEMM b128 read starts (12jj+4g16)%32 ~2-way.
//  (2) activation split by lane group: C rows alternate elems (row r = elem
//      r&1), so lanes 0-15 hold elem0 in reg0 AND lanes 16-31 hold elem1 in
//      reg1. Lanes 0-15 -> elem0, lanes 16-31 -> elem1: halves activation
//      issue, merges c0/c1 into one c register.
//  (3) x chunk prefetch: next chunk's float4 loaded into regs right after the
//      chunk GEMM -> HBM latency hides under the 16 steps, not the barrier.
// NO waves-per-EU cap (r7 lesson: a cap forced VGPR=32 -> weights re-fetched
// from HBM every step -> 35 GB fetch, 12.6 ms).
__global__ __launch_bounds__(512)
void rae_mfma3_kernel(const float* __restrict__ x,
                      const _Float16* __restrict__ WhE, const _Float16* __restrict__ WxE,
                      const float* __restrict__ bih_e, const float* __restrict__ bhh_e,
                      const _Float16* __restrict__ WcH, const float* __restrict__ bc,
                      const _Float16* __restrict__ WdH, const float* __restrict__ bd,
                      float* __restrict__ out) {
  const int t = threadIdx.x;
  const int w = t >> 6;    // wave 0..7
  const int l = t & 63;    // lane
  const int jj = l & 15;   // tile column / A-row selector
  const int g16 = l >> 4;  // K-slice group (frag k = g16*8..g16*8+8)
  const int b = blockIdx.x;

  __shared__ float pre[CH * PST];      // [st][e(514)][col] 65792 B
  __shared__ u32 xraw[2 * CH * XST];   // [e][st][XST u32] 5632 B
  __shared__ u32 hsb[2 * 2 * HST];     // [buf][e][HST u32] 1280 B

  // ---- encoder B-frags: bh[g][kt] = W row (w+8g)*16+jj, halfs kt*32+g16*8 ----
  uint4 bh[4][4];
  float be[4];
#pragma unroll
  for (int g = 0; g < 4; ++g) {
    const int row = (w + 8 * g) * 16 + jj;
#pragma unroll
    for (int kt = 0; kt < 4; ++kt)
      bh[g][kt] = *(const uint4*)(WhE + (size_t)row * 128 + kt * 32 + g16 * 8);
    be[g] = bih_e[row] + bhh_e[row];
  }

  float c = 0.0f;  // cell: lanes 0-15 elem0, lanes 16-31 elem1 (latent w*16+jj)

  for (int i = t; i < 2 * 2 * HST; i += 512) hsb[i] = 0u;  // h = 0 both buffers

  // staging coords: thread -> (elem, step-in-chunk, feature-quad)
  const int se = t >> 8, sst = (t >> 4) & 15, sfq = t & 15;
  const float* xsrc = x + (size_t)b * 2 * Sn * Fn + (size_t)se * Sn * Fn +
                      (size_t)sst * Fn + sfq * 4;
  float4 xv = *(const float4*)xsrc;  // chunk 0 prefetch
  __syncthreads();

  // ================= encoder: 64 chunks x 16 steps =================
  int s = 0;
  for (int ch = 0; ch < NCH; ++ch) {
    {  // write prefetched x chunk fp32->fp16 into xraw
      h2 p0 = {(_Float16)xv.x, (_Float16)xv.y};
      h2 p1 = {(_Float16)xv.z, (_Float16)xv.w};
      xraw[se * (CH * XST) + sst * XST + sfq * 2] = __builtin_bit_cast(u32, p0);
      xraw[se * (CH * XST) + sst * XST + sfq * 2 + 1] = __builtin_bit_cast(u32, p1);
    }
    __syncthreads();
    // ---- chunk GEMM: pre[st][e][col] = x[e,st,:] @ Wx^T[col] + be ----
    {
      uint4 bx0[4], bx1[4];
#pragma unroll
      for (int g = 0; g < 4; ++g) {
        const int row = (w + 8 * g) * 16 + jj;
        bx0[g] = *(const uint4*)(WxE + (size_t)row * 64 + g16 * 8);
        bx1[g] = *(const uint4*)(WxE + (size_t)row * 64 + 32 + g16 * 8);
      }
#pragma unroll
      for (int mt = 0; mt < 2; ++mt) {  // M-tile = elem
        h8 a0 = as_h8(*(const uint4*)&xraw[mt * (CH * XST) + jj * XST + g16 * 4]);
        h8 a1 = as_h8(*(const uint4*)&xraw[mt * (CH * XST) + jj * XST + 16 + g16 * 4]);
#pragma unroll
        for (int g = 0; g < 4; ++g) {
          f4 acc = {be[g], be[g], be[g], be[g]};
          acc = __builtin_amdgcn_mfma_f32_16x16x32_f16(a0, as_h8(bx0[g]), acc, 0, 0, 0);
          acc = __builtin_amdgcn_mfma_f32_16x16x32_f16(a1, as_h8(bx1[g]), acc, 0, 0, 0);
          const int col = (w + 8 * g) * 16 + jj;
#pragma unroll
          for (int r = 0; r < 4; ++r)  // C row = g16*4+r = step-in-chunk
            pre[(g16 * 4 + r) * PST + mt * 514 + col] = acc[r];
        }
      }
    }
    if (ch + 1 < NCH)  // prefetch next chunk under the 16 steps
      xv = *(const float4*)(xsrc + (size_t)(ch + 1) * CH * Fn);
    __syncthreads();
    // ---- 16 recurrence steps ----
    for (int ss = 0; ss < CH; ++ss, ++s) {
      const int cur = s & 1, nx = cur ^ 1;
      const u32* hb = &hsb[(cur * 2 + (jj & 1)) * HST];  // A row = elem jj&1
      f4 a0 = {0.f, 0.f, 0.f, 0.f}, a1 = a0, a2 = a0, a3 = a0;
#pragma unroll
      for (int kt = 0; kt < 4; ++kt) {
        h8 af = as_h8(*(const uint4*)&hb[kt * 16 + g16 * 4]);
        a0 = __builtin_amdgcn_mfma_f32_16x16x32_f16(af, as_h8(bh[0][kt]), a0, 0, 0, 0);
        a1 = __builtin_amdgcn_mfma_f32_16x16x32_f16(af, as_h8(bh[1][kt]), a1, 0, 0, 0);
        a2 = __builtin_amdgcn_mfma_f32_16x16x32_f16(af, as_h8(bh[2][kt]), a2, 0, 0, 0);
        a3 = __builtin_amdgcn_mfma_f32_16x16x32_f16(af, as_h8(bh[3][kt]), a3, 0, 0, 0);
      }
      if (l < 32) {  // lanes 0-15: elem0 (reg0); lanes 16-31: elem1 (reg1)
        const int e = g16;
        const float* pp = &pre[ss * PST + e * 514];
        const float pi = pp[(w + 0) * 16 + jj];
        const float pf = pp[(w + 8) * 16 + jj];
        const float pg = pp[(w + 16) * 16 + jj];
        const float po = pp[(w + 24) * 16 + jj];
        const float gi = fsig((e ? a0[1] : a0[0]) + pi);
        const float gf = fsig((e ? a1[1] : a1[0]) + pf);
        const float gg = __builtin_fmaf(2.f, fsig(2.f * ((e ? a2[1] : a2[0]) + pg)), -1.f);
        const float go = fsig((e ? a3[1] : a3[0]) + po);
        c = __builtin_fmaf(gf, c, gi * gg);
        ((_Float16*)hsb)[(nx * 2 + e) * (2 * HST) + w * 16 + jj] =
            (_Float16)(go * __builtin_fmaf(2.f, fsig(2.f * c), -1.f));
      }
      __syncthreads();
    }
  }

  // ================= decoder: 1024 steps =================
  float bdv[4];
#pragma unroll
  for (int g = 0; g < 4; ++g) {  // reload B-frags with folded W_comb
    const int row = (w + 8 * g) * 16 + jj;
#pragma unroll
    for (int kt = 0; kt < 4; ++kt)
      bh[g][kt] = *(const uint4*)(WcH + (size_t)row * 128 + kt * 32 + g16 * 8);
    bdv[g] = bc[row];
  }
  // dense B-frags (waves 0..3 own output tiles 0..3): out feature = w*16+jj
  uint4 dwf[4];
  float dbias = 0.0f;
  const int od = w * 16 + jj;
  if (w < 4) {
#pragma unroll
    for (int kt = 0; kt < 4; ++kt)
      dwf[kt] = *(const uint4*)(WdH + (size_t)od * 128 + kt * 32 + g16 * 8);
    dbias = bd[od];
  }
  float* outb = out + (size_t)b * 2 * Sn * Fn;

  for (int step = 0; step < Sn; ++step, ++s) {
    const int cur = s & 1, nx = cur ^ 1;
    const u32* hb = &hsb[(cur * 2 + (jj & 1)) * HST];
    f4 a0 = {bdv[0], bdv[0], bdv[0], bdv[0]};
    f4 a1 = {bdv[1], bdv[1], bdv[1], bdv[1]};
    f4 a2 = {bdv[2], bdv[2], bdv[2], bdv[2]};
    f4 a3 = {bdv[3], bdv[3], bdv[3], bdv[3]};
#pragma unroll
    for (int kt = 0; kt < 4; ++kt) {
      h8 af = as_h8(*(const uint4*)&hb[kt * 16 + g16 * 4]);
      a0 = __builtin_amdgcn_mfma_f32_16x16x32_f16(af, as_h8(bh[0][kt]), a0, 0, 0, 0);
      a1 = __builtin_amdgcn_mfma_f32_16x16x32_f16(af, as_h8(bh[1][kt]), a1, 0, 0, 0);
      a2 = __builtin_amdgcn_mfma_f32_16x16x32_f16(af, as_h8(bh[2][kt]), a2, 0, 0, 0);
      a3 = __builtin_amdgcn_mfma_f32_16x16x32_f16(af, as_h8(bh[3][kt]), a3, 0, 0, 0);
    }
    if (l < 32) {  // bias already in acc init
      const int e = g16;
      const float gi = fsig(e ? a0[1] : a0[0]);
      const float gf = fsig(e ? a1[1] : a1[0]);
      const float gg = __builtin_fmaf(2.f, fsig(2.f * (e ? a2[1] : a2[0])), -1.f);
      const float go = fsig(e ? a3[1] : a3[0]);
      c = __builtin_fmaf(gf, c, gi * gg);
      ((_Float16*)hsb)[(nx * 2 + e) * (2 * HST) + w * 16 + jj] =
          (_Float16)(go * __builtin_fmaf(2.f, fsig(2.f * c), -1.f));
    }
    __syncthreads();

    // dense on just-written h (buffer nx): out[2b+e, S-1-step, od].
    // Safe: next iter's h-write targets the other buffer; skew < 1 barrier.
    if (w < 4) {
      const u32* hn = &hsb[(nx * 2 + (jj & 1)) * HST];
      f4 d = {0.f, 0.f, 0.f, 0.f};
#pragma unroll
      for (int kt = 0; kt < 4; ++kt) {
        h8 af = as_h8(*(const uint4*)&hn[kt * 16 + g16 * 4]);
        d = __builtin_amdgcn_mfma_f32_16x16x32_f16(af, as_h8(dwf[kt]), d, 0, 0, 0);
      }
      if (l < 16) {
        const size_t roff = (size_t)(Sn - 1 - step) * Fn + w * 16 + l;
        outb[roff] = d[0] + dbias;                    // elem 0 (C row 0)
        outb[(size_t)Sn * Fn + roff] = d[1] + dbias;  // elem 1 (C row 1)
      }
    }
  }
}

extern "C" void kernel_launch(void* const* d_in, const int* in_sizes, int n_in,
                              void* d_out, int out_size, void* d_ws, size_t ws_size,
                              hipStream_t stream) {
  const float* x     = (const float*)d_in[0];
  const float* Wih_e = (const float*)d_in[1];
  const float* Whh_e = (const float*)d_in[2];
  const float* bih_e = (const float*)d_in[3];
  const float* bhh_e = (const float*)d_in[4];
  const float* Wih_d = (const float*)d_in[5];
  const float* Whh_d = (const float*)d_in[6];
  const float* bih_d = (const float*)d_in[7];
  const float* bhh_d = (const float*)d_in[8];
  const float* Wd    = (const float*)d_in[9];
  const float* bd    = (const float*)d_in[10];
  float* out = (float*)d_out;

  // workspace: only the fixed fp16 weight copies + combined bias (~350 KB)
  _Float16* WhE = (_Float16*)d_ws;           // 512*128
  _Float16* WxE = WhE + Gn * Ln;             // 512*64
  _Float16* WcH = WxE + Gn * Fn;             // 512*128
  _Float16* WdH = WcH + Gn * Ln;             // 64*128
  float* bc = (float*)(WdH + Fn * Ln);       // 512

  pack_kernel<<<256, 256, 0, stream>>>(Wih_e, Whh_e, Wd, WhE, WxE, WdH);
  combine_dec_kernel<<<Gn, Ln, 0, stream>>>(Wih_d, Whh_d, bih_d, bhh_d, Wd, bd, WcH, bc);
  rae_mfma3_kernel<<<Bn / 2, 512, 0, stream>>>(x, WhE, WxE, bih_e, bhh_e,
                                               WcH, bc, WdH, bd, out);
}